// Round 4
// baseline (301.507 us; speedup 1.0000x reference)
//
#include <hip/hip_runtime.h>

#define BB 256
#define II 1152
#define QQ 8
#define JJ 10
#define PP 16

#define BT 16            // b per block (2 per thread: 8 b-lane groups x 16 p-lanes)
#define IT 16            // i per block
#define NBT (BB / BT)    // 16
#define NIT (II / IT)    // 72
#define XROW (IT * QQ + 4)  // 132: +4 pad -> b-rows land on distinct banks

// ---------------------------------------------------------------------------
// Fused routing pass. Thread = (b_l, p) handling batches bA=b0+b_l, bB=bA+8.
// Per i in the tile:
//   w = W[j,i,p,:] loaded ONCE, feeds both batches (2x FMA per load)
//   h{A,B}[j] = w·x{A,B}
//   logit[j]  = reduce_p(v[j,p]·h[j])  (4 shfl_xor; A/B chains interleave)
//   c = softmax_j(logit)  (redundant across p-lanes)
//   sacc[j] += c[j]·h[j]
// No logit tensor: pass2 receives vsum = v0+v1 so b2 = (v0+v1)·hat directly.
// R=0: c uniform 0.1 (softmax of zeros).
// ---------------------------------------------------------------------------
template <int R>
__global__ __launch_bounds__(128, 4) void pass_kernel(
    const float* __restrict__ X,   // [B][I][Q]
    const float* __restrict__ W,   // [J][I][P][Q]
    const float* __restrict__ V,   // R=0: null; R=1: v0; R=2: v0+v1
    float* __restrict__ S)         // [B][J][P] pre-zeroed accumulator
{
    __shared__ float xs[BT * XROW];  // ~8.4 KB

    const int bt = blockIdx.x & (NBT - 1);   // consecutive blocks share i-tile (L2 W reuse)
    const int it = blockIdx.x >> 4;
    const int b0 = bt * BT;
    const int i0 = it * IT;
    const int tid = threadIdx.x;

    // stage x tile: 16 b x 16 i x 8 q = 2048 floats = 512 float4, 4 per thread
#pragma unroll
    for (int k = 0; k < 4; ++k) {
        const int f4  = tid + k * 128;   // 0..511
        const int b_l = f4 >> 5;         // 32 float4 per b-row
        const int r   = f4 & 31;
        const float4 v4 = ((const float4*)(X + ((size_t)(b0 + b_l) * II + i0) * QQ))[r];
        ((float4*)(xs + b_l * XROW))[r] = v4;
    }
    __syncthreads();

    const int b_l = tid >> 4;   // 0..7
    const int p   = tid & 15;
    const int bA  = b0 + b_l;
    const int bB  = bA + 8;

    float vvA[JJ], vvB[JJ];
    if (R > 0) {
#pragma unroll
        for (int j = 0; j < JJ; ++j) {
            vvA[j] = V[((size_t)bA * JJ + j) * PP + p];
            vvB[j] = V[((size_t)bB * JJ + j) * PP + p];
        }
    }

    float saccA[JJ], saccB[JJ];
#pragma unroll
    for (int j = 0; j < JJ; ++j) { saccA[j] = 0.0f; saccB[j] = 0.0f; }

    for (int i = 0; i < IT; ++i) {
        const float4 a0 = *(const float4*)(xs + b_l * XROW + i * QQ);
        const float4 a1 = *(const float4*)(xs + b_l * XROW + i * QQ + 4);
        const float4 e0 = *(const float4*)(xs + (b_l + 8) * XROW + i * QQ);
        const float4 e1 = *(const float4*)(xs + (b_l + 8) * XROW + i * QQ + 4);

        float hA[JJ], hB[JJ];
#pragma unroll
        for (int j = 0; j < JJ; ++j) {
            const float4* wp = (const float4*)(W + (((size_t)j * II + i0 + i) * PP + p) * QQ);
            const float4 w0 = wp[0];
            const float4 w1 = wp[1];
            hA[j] = w0.x * a0.x + w0.y * a0.y + w0.z * a0.z + w0.w * a0.w +
                    w1.x * a1.x + w1.y * a1.y + w1.z * a1.z + w1.w * a1.w;
            hB[j] = w0.x * e0.x + w0.y * e0.y + w0.z * e0.z + w0.w * e0.w +
                    w1.x * e1.x + w1.y * e1.y + w1.z * e1.z + w1.w * e1.w;
        }

        float cA[JJ], cB[JJ];
        if (R == 0) {
#pragma unroll
            for (int j = 0; j < JJ; ++j) { cA[j] = 0.1f; cB[j] = 0.1f; }
        } else {
            float bjA[JJ], bjB[JJ];
#pragma unroll
            for (int j = 0; j < JJ; ++j) {
                float dA = vvA[j] * hA[j];
                float dB = vvB[j] * hB[j];
                dA += __shfl_xor(dA, 1, 64);  dB += __shfl_xor(dB, 1, 64);
                dA += __shfl_xor(dA, 2, 64);  dB += __shfl_xor(dB, 2, 64);
                dA += __shfl_xor(dA, 4, 64);  dB += __shfl_xor(dB, 4, 64);
                dA += __shfl_xor(dA, 8, 64);  dB += __shfl_xor(dB, 8, 64);
                bjA[j] = dA;  bjB[j] = dB;
            }
            float mA = bjA[0], mB = bjB[0];
#pragma unroll
            for (int j = 1; j < JJ; ++j) { mA = fmaxf(mA, bjA[j]); mB = fmaxf(mB, bjB[j]); }
            float sA = 0.0f, sB = 0.0f;
#pragma unroll
            for (int j = 0; j < JJ; ++j) {
                cA[j] = __expf(bjA[j] - mA);  sA += cA[j];
                cB[j] = __expf(bjB[j] - mB);  sB += cB[j];
            }
            const float iA = 1.0f / sA, iB = 1.0f / sB;
#pragma unroll
            for (int j = 0; j < JJ; ++j) { cA[j] *= iA; cB[j] *= iB; }
        }

#pragma unroll
        for (int j = 0; j < JJ; ++j) {
            saccA[j] += cA[j] * hA[j];
            saccB[j] += cB[j] * hB[j];
        }
    }

#pragma unroll
    for (int j = 0; j < JJ; ++j) {
        atomicAdd(&S[((size_t)bA * JJ + j) * PP + p], saccA[j]);
        atomicAdd(&S[((size_t)bB * JJ + j) * PP + p], saccB[j]);
    }
}

// ---------------------------------------------------------------------------
// squash row of 16: v = s*|s|^2/(1+|s|^2)/sqrt(|s|^2+1e-7).
// ADD_PREV: out = squash(s) + prev (builds vsum = v1 + v0 for pass 2).
// ZERO_S: re-zero s for the next pass's atomics (replaces a memset dispatch).
// ---------------------------------------------------------------------------
template <int ZERO_S, int ADD_PREV>
__global__ __launch_bounds__(256) void squash_kernel(float* __restrict__ S,
                                                     const float* __restrict__ PREV,
                                                     float* __restrict__ V)
{
    const int idx = blockIdx.x * blockDim.x + threadIdx.x;  // (b*J + j)
    if (idx >= BB * JJ) return;
    float4* sp = (float4*)(S + idx * PP);
    float4 a = sp[0], b4 = sp[1], c4 = sp[2], d4 = sp[3];
    float s2 = a.x * a.x + a.y * a.y + a.z * a.z + a.w * a.w +
               b4.x * b4.x + b4.y * b4.y + b4.z * b4.z + b4.w * b4.w +
               c4.x * c4.x + c4.y * c4.y + c4.z * c4.z + c4.w * c4.w +
               d4.x * d4.x + d4.y * d4.y + d4.z * d4.z + d4.w * d4.w;
    const float scale = s2 / (1.0f + s2) / sqrtf(s2 + 1e-7f);
    a.x *= scale; a.y *= scale; a.z *= scale; a.w *= scale;
    b4.x *= scale; b4.y *= scale; b4.z *= scale; b4.w *= scale;
    c4.x *= scale; c4.y *= scale; c4.z *= scale; c4.w *= scale;
    d4.x *= scale; d4.y *= scale; d4.z *= scale; d4.w *= scale;
    if (ADD_PREV) {
        const float4* pp = (const float4*)(PREV + idx * PP);
        const float4 p0 = pp[0], p1 = pp[1], p2 = pp[2], p3 = pp[3];
        a.x += p0.x; a.y += p0.y; a.z += p0.z; a.w += p0.w;
        b4.x += p1.x; b4.y += p1.y; b4.z += p1.z; b4.w += p1.w;
        c4.x += p2.x; c4.y += p2.y; c4.z += p2.z; c4.w += p2.w;
        d4.x += p3.x; d4.y += p3.y; d4.z += p3.z; d4.w += p3.w;
    }
    float4* vp = (float4*)(V + idx * PP);
    vp[0] = a; vp[1] = b4; vp[2] = c4; vp[3] = d4;
    if (ZERO_S) {
        const float4 z = {0.0f, 0.0f, 0.0f, 0.0f};
        sp[0] = z; sp[1] = z; sp[2] = z; sp[3] = z;
    }
}

extern "C" void kernel_launch(void* const* d_in, const int* in_sizes, int n_in,
                              void* d_out, int out_size, void* d_ws, size_t ws_size,
                              hipStream_t stream)
{
    const float* X = (const float*)d_in[0];  // [256][1152][8]
    const float* W = (const float*)d_in[1];  // [10][1152][16][8]
    float* out = (float*)d_out;              // [256][10][16]

    float* s  = (float*)d_ws;        // 40960 floats
    float* v0 = s + BB * JJ * PP;    // 40960 floats
    float* vs = v0 + BB * JJ * PP;   // 40960 floats (vsum = v0+v1); total 480 KB

    const int grid = NBT * NIT;  // 1152 blocks of 128 threads

    hipMemsetAsync(s, 0, BB * JJ * PP * sizeof(float), stream);
    pass_kernel<0><<<grid, 128, 0, stream>>>(X, W, nullptr, s);
    squash_kernel<1, 0><<<10, 256, 0, stream>>>(s, nullptr, v0);   // v0; s=0
    pass_kernel<1><<<grid, 128, 0, stream>>>(X, W, v0, s);
    squash_kernel<1, 1><<<10, 256, 0, stream>>>(s, v0, vs);        // vs = v1+v0; s=0
    pass_kernel<2><<<grid, 128, 0, stream>>>(X, W, vs, s);
    squash_kernel<0, 0><<<10, 256, 0, stream>>>(s, nullptr, out);  // output
}